// Round 1
// 429.184 us; speedup vs baseline: 1.0154x; 1.0154x over previous
//
#include <hip/hip_runtime.h>
#include <math.h>

#define HDIM 7168
#define NEXP 256
#define NTOK 8192
#define BM 128
#define KS 4
#define KCH (HDIM / KS)      // 1792 source-k per block
#define NR (KCH / 32)        // 56 rounds of 32 source-k
#define PITCH 72             // f16 slots per LDS row: 32 hi | 32 lo | 8 pad

typedef _Float16 f16x8 __attribute__((ext_vector_type(8)));
typedef float f32x4 __attribute__((ext_vector_type(4)));

__device__ __forceinline__ f16x8 hi8(float4 u, float4 v) {
    f16x8 h;
    h[0] = (_Float16)u.x; h[1] = (_Float16)u.y; h[2] = (_Float16)u.z; h[3] = (_Float16)u.w;
    h[4] = (_Float16)v.x; h[5] = (_Float16)v.y; h[6] = (_Float16)v.z; h[7] = (_Float16)v.w;
    return h;
}
__device__ __forceinline__ f16x8 lo8(float4 u, float4 v, f16x8 h) {
    f16x8 l;
    l[0] = (_Float16)(u.x - (float)h[0]); l[1] = (_Float16)(u.y - (float)h[1]);
    l[2] = (_Float16)(u.z - (float)h[2]); l[3] = (_Float16)(u.w - (float)h[3]);
    l[4] = (_Float16)(v.x - (float)h[4]); l[5] = (_Float16)(v.y - (float)h[5]);
    l[6] = (_Float16)(v.z - (float)h[6]); l[7] = (_Float16)(v.w - (float)h[7]);
    return l;
}

// ---------------------------------------------------------------------------
// Router GEMM via f16 MFMA 2-term split: logits = hs @ W^T.
// a = ah + al (f16 each); C = Ah*Bh + Ah*Bl + Al*Bh  (al*bl ~ 2^-20, dropped).
// W scaled x256 in-reg so W_lo is f16-normal; epilogue multiplies by 1/256.
// Verified layouts (learn_hip m89/m91/m120): A/B frag [idx=lane&15][k=quad*8+j],
// C/D col=lane&15, row=quad*4+reg.
//
// v2 structure: BN=256 (full N) so A is fetched+converted exactly once.
//   Block 128x256, 512 thr, 8 waves as 2x4, wave tile 64x64 (4x4 16-tiles).
//   A: global->reg->convert->LDS, double-buffered (one barrier per round).
//   B: per-lane fp32 fragment loads straight from global (L2-resident slice;
//      grid.x = k-split so each XCD's L2 holds one 1.83 MB W k-slice),
//      converted to hi/lo in registers -- no B LDS traffic at all.
//   Grid (4 ks, 64 m) = 256 blocks = 1 block/CU, 2 waves/SIMD.
// ---------------------------------------------------------------------------
__global__ __launch_bounds__(512, 2)
void router_gemm_mfma(const float* __restrict__ hs,
                      const float* __restrict__ W,
                      float* __restrict__ logits)
{
    __shared__ __align__(16) _Float16 Alds[2][BM * PITCH];   // 2 x 18432 B

    const int tid  = threadIdx.x;
    const int lane = tid & 63;
    const int wave = tid >> 6;           // 0..7
    const int kb = blockIdx.x * KCH;     // k-split offset
    const int bm = blockIdx.y * BM;

    const int wm = (wave >> 2) << 6;     // wave row band: 0 / 64
    const int wc = wave & 3;             // wave col band: wc*64
    const int fm = lane & 15;
    const int quad = lane >> 4;

    // A staging: thread -> row tid>>2 (0..127), k-eighth (tid&3)*8
    const int arow = tid >> 2;
    const int akh  = (tid & 3) << 3;
    const float* Ap = hs + (size_t)(bm + arow) * HDIM + kb + akh;
    // B frag source: lane covers W row (wc*64 + in_*16 + fm), k = quad*8..+7
    const float* Bp = W + (size_t)(wc * 64 + fm) * HDIM + kb + quad * 8;

    f32x4 acc[4][4];
#pragma unroll
    for (int i = 0; i < 4; i++)
#pragma unroll
        for (int j = 0; j < 4; j++) acc[i][j] = (f32x4)0.0f;

    // ---- prologue: prefetch round 0 (A 8 floats, B 4 tiles x 8 floats) ----
    float4 a0 = *(const float4*)(Ap + 0);
    float4 a1 = *(const float4*)(Ap + 4);
    float4 bu[4], bv[4];
#pragma unroll
    for (int i = 0; i < 4; i++) {
        const float* q = Bp + (size_t)i * (16 * HDIM);
        bu[i] = *(const float4*)(q + 0);
        bv[i] = *(const float4*)(q + 4);
    }
    {   // stage A round 0 into buffer 0
        f16x8 h = hi8(a0, a1);
        f16x8 l = lo8(a0, a1, h);
        *(f16x8*)&Alds[0][arow * PITCH + akh]      = h;
        *(f16x8*)&Alds[0][arow * PITCH + 32 + akh] = l;
    }
    __syncthreads();

#pragma unroll 2
    for (int r = 0; r < NR; ++r) {
        const int cur = r & 1;
        // ---- B: convert prefetched fp32 (x256) to hi/lo f16 frags ----
        f16x8 bh[4], bl[4];
#pragma unroll
        for (int i = 0; i < 4; i++) {
            float4 s0 = make_float4(bu[i].x * 256.0f, bu[i].y * 256.0f,
                                    bu[i].z * 256.0f, bu[i].w * 256.0f);
            float4 s1 = make_float4(bv[i].x * 256.0f, bv[i].y * 256.0f,
                                    bv[i].z * 256.0f, bv[i].w * 256.0f);
            bh[i] = hi8(s0, s1);
            bl[i] = lo8(s0, s1, bh[i]);
        }
        // ---- prefetch next round (latency hidden under MFMA phase) ----
        if (r + 1 < NR) {
            const float* An = Ap + (r + 1) * 32;
            a0 = *(const float4*)(An + 0);
            a1 = *(const float4*)(An + 4);
            const float* Bn = Bp + (r + 1) * 32;
#pragma unroll
            for (int i = 0; i < 4; i++) {
                const float* q = Bn + (size_t)i * (16 * HDIM);
                bu[i] = *(const float4*)(q + 0);
                bv[i] = *(const float4*)(q + 4);
            }
        }
        // ---- A frags from LDS (PITCH=72: conflict-free 2-way reads) ----
        f16x8 af[4], alo[4];
#pragma unroll
        for (int im = 0; im < 4; im++) {
            const int off = (wm + im * 16 + fm) * PITCH + quad * 8;
            af[im]  = *(const f16x8*)&Alds[cur][off];
            alo[im] = *(const f16x8*)&Alds[cur][off + 32];
        }
        // ---- MFMA: 48 per wave over this 32-k chunk ----
        // P1: Ah * Bh
#pragma unroll
        for (int im = 0; im < 4; im++)
#pragma unroll
            for (int in_ = 0; in_ < 4; in_++)
                acc[im][in_] = __builtin_amdgcn_mfma_f32_16x16x32_f16(af[im], bh[in_], acc[im][in_], 0, 0, 0);
        // P2: Ah * Bl
#pragma unroll
        for (int im = 0; im < 4; im++)
#pragma unroll
            for (int in_ = 0; in_ < 4; in_++)
                acc[im][in_] = __builtin_amdgcn_mfma_f32_16x16x32_f16(af[im], bl[in_], acc[im][in_], 0, 0, 0);
        // P3: Al * Bh
#pragma unroll
        for (int im = 0; im < 4; im++)
#pragma unroll
            for (int in_ = 0; in_ < 4; in_++)
                acc[im][in_] = __builtin_amdgcn_mfma_f32_16x16x32_f16(alo[im], bh[in_], acc[im][in_], 0, 0, 0);
        // ---- stage next-round A into the other buffer ----
        if (r + 1 < NR) {
            f16x8 h = hi8(a0, a1);
            f16x8 l = lo8(a0, a1, h);
            *(f16x8*)&Alds[cur ^ 1][arow * PITCH + akh]      = h;
            *(f16x8*)&Alds[cur ^ 1][arow * PITCH + 32 + akh] = l;
        }
        __syncthreads();
    }

    // ---- epilogue: undo x256 on B, combine K-splits via atomics ----
#pragma unroll
    for (int im = 0; im < 4; im++) {
#pragma unroll
        for (int in_ = 0; in_ < 4; in_++) {
            const int n = wc * 64 + in_ * 16 + fm;
#pragma unroll
            for (int rr = 0; rr < 4; rr++) {
                const int m = bm + wm + im * 16 + quad * 4 + rr;
                unsafeAtomicAdd(&logits[(size_t)m * NEXP + n], acc[im][in_][rr] * 0.00390625f);
            }
        }
    }
}

// ---------------------------------------------------------------------------
// Kernel 2: one wave per token. lane l holds experts 4l..4l+3.
// Replicates jax.lax.top_k semantics exactly: descending, ties -> lower index;
// unselected groups contribute literal 0.0f candidates.
// ---------------------------------------------------------------------------
__global__ __launch_bounds__(256)
void router_topk_kernel(const float* __restrict__ logits,
                        const float* __restrict__ bias,
                        const float* __restrict__ corr,
                        float* __restrict__ out)
{
    const int lane = threadIdx.x & 63;
    const int wave = threadIdx.x >> 6;
    const int t = blockIdx.x * 4 + wave;
    const float* row = logits + (size_t)t * NEXP;
    const int e0 = lane << 2;

    float4 lg = *(const float4*)(row + e0);
    float4 bb = *(const float4*)(bias + e0);
    float4 cc = *(const float4*)(corr + e0);

    float xs[4] = {lg.x + bb.x, lg.y + bb.y, lg.z + bb.z, lg.w + bb.w};
    float cs[4] = {cc.x, cc.y, cc.z, cc.w};
    float s[4], sc[4], mv[4];
#pragma unroll
    for (int i = 0; i < 4; i++) {
        s[i] = 1.0f / (1.0f + expf(-xs[i]));
        sc[i] = s[i] + cs[i];
    }

    // ---- per-group (32 experts = 8 lanes) top-2 sum ----
    float m1 = fmaxf(sc[0], sc[1]);
    float m2 = fminf(sc[0], sc[1]);
    if (sc[2] > m1) { m2 = m1; m1 = sc[2]; } else { m2 = fmaxf(m2, sc[2]); }
    if (sc[3] > m1) { m2 = m1; m1 = sc[3]; } else { m2 = fmaxf(m2, sc[3]); }
#pragma unroll
    for (int off = 1; off <= 4; off <<= 1) {
        float o1 = __shfl_xor(m1, off);
        float o2 = __shfl_xor(m2, off);
        float hi = fmaxf(m1, o1);
        float lo = fminf(m1, o1);
        m1 = hi;
        m2 = fmaxf(lo, fmaxf(m2, o2));
    }
    const float gscore = m1 + m2;

    // ---- broadcast all 8 group scores, compute top-4 group mask ----
    float gs[8];
#pragma unroll
    for (int j = 0; j < 8; j++) gs[j] = __shfl(gscore, j << 3);
    const int g = lane >> 3;
    int rank = 0;
#pragma unroll
    for (int j = 0; j < 8; j++)
        rank += ((gs[j] > gs[g]) || ((gs[j] == gs[g]) && (j < g))) ? 1 : 0;
    const bool sel = (rank < 4);

#pragma unroll
    for (int i = 0; i < 4; i++) mv[i] = sel ? sc[i] : 0.0f;

    // ---- iterative top-8 wave argmax (stable: ties -> lower index) ----
    int oidx[8];
    float ow[8];
    float wsum = 0.0f;
#pragma unroll
    for (int r = 0; r < 8; r++) {
        float bv = mv[0]; int bi = e0;
        if (mv[1] > bv) { bv = mv[1]; bi = e0 + 1; }
        if (mv[2] > bv) { bv = mv[2]; bi = e0 + 2; }
        if (mv[3] > bv) { bv = mv[3]; bi = e0 + 3; }
#pragma unroll
        for (int off = 32; off >= 1; off >>= 1) {
            float ov = __shfl_xor(bv, off);
            int oi = __shfl_xor(bi, off);
            if ((ov > bv) || ((ov == bv) && (oi < bi))) { bv = ov; bi = oi; }
        }
        // all lanes now agree on (bv, bi)
        const int wl = bi >> 2;
        const int slot = bi & 3;
        float sraw = (slot == 0) ? s[0] : (slot == 1) ? s[1] : (slot == 2) ? s[2] : s[3];
        sraw = __shfl(sraw, wl);
        if (lane == wl) {
            if (slot == 0) mv[0] = -1e30f;
            else if (slot == 1) mv[1] = -1e30f;
            else if (slot == 2) mv[2] = -1e30f;
            else mv[3] = -1e30f;
        }
        oidx[r] = bi;
        ow[r] = sraw;
        wsum += sraw;
    }

    if (lane == 0) {
        const float d = wsum + 1e-20f;
        float* oi_p = out + (size_t)t * 8;
        float* ow_p = out + (size_t)NTOK * 8 + (size_t)t * 8;
#pragma unroll
        for (int r = 0; r < 8; r++) {
            oi_p[r] = (float)oidx[r];
            ow_p[r] = (ow[r] / d) * 2.5f;
        }
    }
}

extern "C" void kernel_launch(void* const* d_in, const int* in_sizes, int n_in,
                              void* d_out, int out_size, void* d_ws, size_t ws_size,
                              hipStream_t stream)
{
    const float* hs   = (const float*)d_in[0];   // [8192, 7168]
    const float* W    = (const float*)d_in[1];   // [256, 7168]
    const float* b    = (const float*)d_in[2];   // [256]
    const float* corr = (const float*)d_in[3];   // [256]
    float* out = (float*)d_out;                  // 65536 idx-as-float + 65536 weights
    float* logits = (float*)d_ws;                // 8192*256 fp32 = 8 MB scratch

    // zero the logits accumulator (split-K atomics land here)
    hipMemsetAsync(logits, 0, (size_t)NTOK * NEXP * sizeof(float), stream);

    dim3 g1(KS, NTOK / BM);                      // (4, 64) -> 256 blocks, 1/CU
    router_gemm_mfma<<<g1, 512, 0, stream>>>(hs, W, logits);
    router_topk_kernel<<<NTOK / 4, 256, 0, stream>>>(logits, b, corr, out);
}